// Round 21
// baseline (105.117 us; speedup 1.0000x reference)
//
#include <hip/hip_runtime.h>
#include <math.h>

#define B_  4
#define C_  256
#define CI_ 128
#define N_  4096
#define D_  128
#define KVSPLIT 4
#define KVQ  (N_ / KVSPLIT)
#define KVT  64
#define NT   (KVQ / KVT)
#define LOG2E 1.4426950408889634f

typedef _Float16 f16;
typedef f16 f16x8 __attribute__((ext_vector_type(8)));
typedef __fp16 fp16x2 __attribute__((ext_vector_type(2)));
typedef float f32x4 __attribute__((ext_vector_type(4)));
typedef unsigned short u16;

__device__ __forceinline__ u16 f2h(float x) {
    union { f16 h; u16 u; } v; v.h = (f16)x; return v.u;
}
__device__ __forceinline__ unsigned pkrtz(float a, float b) {
    union { fp16x2 h; unsigned u; } v;
    v.h = __builtin_amdgcn_cvt_pkrtz(a, b);
    return v.u;
}

__device__ __forceinline__ void gll16(const void* g, void* l) {
    __builtin_amdgcn_global_load_lds(
        (const __attribute__((address_space(1))) void*)g,
        (__attribute__((address_space(3))) void*)l, 16, 0, 0);
}

// ---------------------------------------------------------------------------
// Embedding conv1x1, f16 MFMA, double-buffered LDS (1 barrier/chunk),
// BALANCED: one conv per grid plane.  grid (N/64, B, 3), block 256.
// which 0: theta(x)*LOG2E -> th[n][ci]; 1: phi(src) -> ph[n][ci];
// which 2: g(src) -> gt[ci][n].
// ---------------------------------------------------------------------------
__global__ __launch_bounds__(256) void embed_kernel(
    const float* __restrict__ x, const float* __restrict__ src,
    const float* __restrict__ g_w, const float* __restrict__ g_b,
    const float* __restrict__ th_w, const float* __restrict__ th_b,
    const float* __restrict__ ph_w, const float* __restrict__ ph_b,
    u16* __restrict__ th, u16* __restrict__ ph, u16* __restrict__ gt)
{
    __shared__ u16 xh[2][64 * 40];

    const int n0 = blockIdx.x * 64, b = blockIdx.y, which = blockIdx.z;
    const float* in   = which ? src : x;
    const float* wm   = (which == 0) ? th_w : (which == 1 ? ph_w : g_w);
    const float* bias = (which == 0) ? th_b : (which == 1 ? ph_b : g_b);
    const float wscale = (which == 0) ? LOG2E : 1.0f;

    const int t = threadIdx.x, lane = t & 63, wv = t >> 6;
    const int lq = lane & 15, lh = lane >> 4;
    const int mf0 = wv * 2, cq = t >> 6;

    f32x4 acc[2][4];
#pragma unroll
    for (int m = 0; m < 2; ++m) {
        float b0 = bias[16 * (mf0 + m) + 4 * lh + 0] * wscale;
        float b1 = bias[16 * (mf0 + m) + 4 * lh + 1] * wscale;
        float b2 = bias[16 * (mf0 + m) + 4 * lh + 2] * wscale;
        float b3 = bias[16 * (mf0 + m) + 4 * lh + 3] * wscale;
#pragma unroll
        for (int s = 0; s < 4; ++s) acc[m][s] = (f32x4){b0, b1, b2, b3};
    }

    const float* colbase = in + (size_t)b * C_ * N_ + n0;

    float iv[2][8];
    f16x8 wf_[2][2];

    auto load_inputs = [&](int slot, int k) {
        const int c0 = k * 32;
#pragma unroll
        for (int p = 0; p < 2; ++p) {
            int cl = 16 * p + 4 * cq;
#pragma unroll
            for (int e = 0; e < 4; ++e)
                iv[slot][4 * p + e] = colbase[(size_t)(c0 + cl + e) * N_ + lane];
        }
    };
    auto load_weights = [&](int slot, int k) {
        const int c0 = k * 32;
#pragma unroll
        for (int m = 0; m < 2; ++m) {
            const float* wp = wm + (size_t)(16 * (mf0 + m) + lq) * C_ + c0 + 8 * lh;
            float4 a = *(const float4*)wp;
            float4 bq = *(const float4*)(wp + 4);
            wf_[slot][m][0] = (f16)(a.x * wscale);  wf_[slot][m][1] = (f16)(a.y * wscale);
            wf_[slot][m][2] = (f16)(a.z * wscale);  wf_[slot][m][3] = (f16)(a.w * wscale);
            wf_[slot][m][4] = (f16)(bq.x * wscale); wf_[slot][m][5] = (f16)(bq.y * wscale);
            wf_[slot][m][6] = (f16)(bq.z * wscale); wf_[slot][m][7] = (f16)(bq.w * wscale);
        }
    };
    auto write_lds = [&](int slot) {
#pragma unroll
        for (int p = 0; p < 2; ++p) {
            int cl = 16 * p + 4 * cq;
            union { f16 h[4]; ushort4 u; } cv;
            cv.h[0] = (f16)iv[slot][4 * p + 0];
            cv.h[1] = (f16)iv[slot][4 * p + 1];
            cv.h[2] = (f16)iv[slot][4 * p + 2];
            cv.h[3] = (f16)iv[slot][4 * p + 3];
            *(ushort4*)&xh[slot][lane * 40 + cl] = cv.u;
        }
    };

    // prologue: chunk 0 -> slot 0 (regs + LDS), chunk 1 -> slot 1 (regs)
    load_inputs(0, 0);
    load_weights(0, 0);
    write_lds(0);
    load_inputs(1, 1);
    load_weights(1, 1);

#pragma unroll
    for (int k = 0; k < 8; ++k) {
        const int cur = k & 1, nxt = cur ^ 1;
        __syncthreads();                 // xh[cur] writes visible; xh[nxt] free
        if (k < 7) write_lds(nxt);       // chunk k+1 regs -> LDS
        if (k < 6) load_inputs(cur, k + 2);   // iv[cur] dead -> prefetch k+2

#pragma unroll
        for (int s = 0; s < 4; ++s) {
            f16x8 xf = *(const f16x8*)&xh[cur][(16 * s + lq) * 40 + 8 * lh];
#pragma unroll
            for (int m = 0; m < 2; ++m)
                acc[m][s] = __builtin_amdgcn_mfma_f32_16x16x32_f16(wf_[cur][m], xf, acc[m][s], 0, 0, 0);
        }
        if (k < 6) load_weights(cur, k + 2);  // wf_[cur] consumed by MFMA above
    }

    // epilogue. D-layout: col(n)=lq, row(ci)=16*mf+4*lh+reg
    if (which < 2) {
        u16* op = (which == 0 ? th : ph) + (size_t)b * N_ * CI_;
#pragma unroll
        for (int m = 0; m < 2; ++m)
#pragma unroll
            for (int s = 0; s < 4; ++s) {
                ushort4 pk = {f2h(acc[m][s][0]), f2h(acc[m][s][1]),
                              f2h(acc[m][s][2]), f2h(acc[m][s][3])};
                *(ushort4*)(op + (size_t)(n0 + 16 * s + lq) * CI_ + 16 * (mf0 + m) + 4 * lh) = pk;
            }
    } else {
        u16* gb2 = gt + (size_t)b * CI_ * N_;
#pragma unroll
        for (int m = 0; m < 2; ++m)
#pragma unroll
            for (int s = 0; s < 4; ++s)
#pragma unroll
                for (int r = 0; r < 4; ++r)
                    gb2[(size_t)(16 * (mf0 + m) + 4 * lh + r) * N_ + n0 + 16 * s + lq] =
                        f2h(acc[m][s][r]);
    }
}

// ---------------------------------------------------------------------------
// Flash attention, f16 MFMA, single-barrier double-buffered, KVT=64.
// grid (N/128, B, 4), block 256 (4 waves x 32 q).  r19 kernel (63.5 us)
// + T5 s_setprio(1) around both MFMA clusters (2 blocks/CU at skewed
// phases -> scheduler can favor the MFMA-issuing wave, m191 regime).
// ---------------------------------------------------------------------------
__global__ __launch_bounds__(256, 2) void attn_kernel(
    const u16* __restrict__ th, const u16* __restrict__ ph,
    const u16* __restrict__ gt, u16* __restrict__ part, float* __restrict__ ml)
{
    __shared__ u16 Ks[2][KVT * 128];     // 2 x 16KB, row rr: 128 u16
    __shared__ u16 Vt[2][64 * 128];      // 2 x 16KB, pair-row: 2d x 64kv
    __shared__ unsigned Pl[4][16 * 36];  // 9KB, per-wave P exchange

    const int n0 = blockIdx.x * 128, b = blockIdx.y, sp = blockIdx.z;
    const int t = threadIdx.x, wv = t >> 6, lane = t & 63;
    const int lq = lane & 15, lh = lane >> 4;
    const int q0w = n0 + wv * 32;

    const u16* kb = ph + ((size_t)b * N_ + (size_t)sp * KVQ) * D_;
    const u16* vb = gt + (size_t)b * D_ * N_ + sp * KVQ;

    f16x8 qf[2][4];
#pragma unroll
    for (int qs = 0; qs < 2; ++qs) {
        const u16* qp = th + ((size_t)b * N_ + q0w + 16 * qs + lq) * D_ + 8 * lh;
#pragma unroll
        for (int c = 0; c < 4; ++c) qf[qs][c] = *(const f16x8*)(qp + 32 * c);
    }

    f32x4 Ot[2][8];
#pragma unroll
    for (int qs = 0; qs < 2; ++qs)
#pragma unroll
        for (int j = 0; j < 8; ++j) Ot[qs][j] = (f32x4){0.f, 0.f, 0.f, 0.f};
    float m_run[2] = {-INFINITY, -INFINITY};
    float l_run[2] = {0.f, 0.f};

    auto stage = [&](int buf, int it) {
        const int kv0 = it * KVT;
#pragma unroll
        for (int ii = 0; ii < 4; ++ii) {
            int i = 4 * wv + ii;                    // 0..15
            int rr = 4 * i + (lane >> 4);           // kv row 0..63
            const u16* g = kb + (size_t)(kv0 + rr) * D_ + (((lane & 15) ^ (rr & 7)) * 8);
            gll16(g, &Ks[buf][i * 512]);
        }
#pragma unroll
        for (int jj = 0; jj < 4; ++jj) {
            int j = 4 * wv + jj;                    // 0..15, 4 pair-rows each
            int r = 4 * j + (lane >> 4);            // pair-row 0..63 (256B rows)
            int s = lane & 15;                      // linear slot (16B)
            int c6 = s ^ (r & 7);                   // swizzled logical slot
            int dd = 2 * r + (c6 >> 3);             // d row 0..127
            const u16* g = vb + (size_t)dd * N_ + kv0 + (c6 & 7) * 8;
            gll16(g, &Vt[buf][j * 512]);
        }
    };

    stage(0, 0);
    for (int it = 0; it < NT; ++it) {
        __syncthreads();                       // drains vmcnt -> buf[it&1] ready
        if (it + 1 < NT) stage((it + 1) & 1, it + 1);   // flies under compute
        const u16* K = Ks[it & 1];
        const u16* V = Vt[it & 1];

        // ---- S^T = K Q^T : lane holds S(q=lq, kv=16tt+4lh+r), tt 0..3 ----
        f32x4 S[2][4];
#pragma unroll
        for (int qs = 0; qs < 2; ++qs)
#pragma unroll
            for (int tt = 0; tt < 4; ++tt) S[qs][tt] = (f32x4){0.f, 0.f, 0.f, 0.f};
        __builtin_amdgcn_s_setprio(1);
#pragma unroll
        for (int c = 0; c < 4; ++c)
#pragma unroll
            for (int tt = 0; tt < 4; ++tt) {
                int row = 16 * tt + lq;
                f16x8 kf = *(const f16x8*)&K[row * 128 + ((32 * c + 8 * lh) ^ ((row & 7) << 3))];
                S[0][tt] = __builtin_amdgcn_mfma_f32_16x16x32_f16(kf, qf[0][c], S[0][tt], 0, 0, 0);
                S[1][tt] = __builtin_amdgcn_mfma_f32_16x16x32_f16(kf, qf[1][c], S[1][tt], 0, 0, 0);
            }
        __builtin_amdgcn_s_setprio(0);

        // ---- per-lane online softmax (base-2) + P exchange via wave-LDS ----
        f16x8 pf[2][2];
#pragma unroll
        for (int qs = 0; qs < 2; ++qs) {
            float mx = -INFINITY;
#pragma unroll
            for (int tt = 0; tt < 4; ++tt)
#pragma unroll
                for (int r = 0; r < 4; ++r) mx = fmaxf(mx, S[qs][tt][r]);
            mx = fmaxf(mx, __shfl_xor(mx, 16));
            mx = fmaxf(mx, __shfl_xor(mx, 32));
            if (!__all(mx <= m_run[qs])) {       // exact skip: al==1 otherwise
                float mn = fmaxf(m_run[qs], mx);
                float al = exp2f(m_run[qs] - mn);
                m_run[qs] = mn;
                l_run[qs] *= al;
#pragma unroll
                for (int j = 0; j < 8; ++j) Ot[qs][j] *= al;
            }
            float p[4][4];
            float ls = 0.f;
#pragma unroll
            for (int tt = 0; tt < 4; ++tt)
#pragma unroll
                for (int r = 0; r < 4; ++r) {
                    p[tt][r] = exp2f(S[qs][tt][r] - m_run[qs]);
                    ls += p[tt][r];
                }
            ls += __shfl_xor(ls, 16);
            ls += __shfl_xor(ls, 32);
            l_run[qs] += ls;

            // write P pairs: row q=lq (stride 36 u32), u32 idx 8tt+2lh+{0,1}
            unsigned* pw = &Pl[wv][lq * 36];
#pragma unroll
            for (int tt = 0; tt < 4; ++tt) {
                uint2 wpair;
                wpair.x = pkrtz(p[tt][0], p[tt][1]);
                wpair.y = pkrtz(p[tt][2], p[tt][3]);
                *(uint2*)(pw + 8 * tt + 2 * lh) = wpair;     // ds_write_b64
            }
            // read B-frags: kv = 32cc + 8lh..+7 -> u32 16cc + 4lh..+3
            union { uint4 u; f16x8 v; } pu0, pu1;
            pu0.u = *(const uint4*)(pw + 4 * lh);            // ds_read_b128
            pu1.u = *(const uint4*)(pw + 16 + 4 * lh);
            pf[qs][0] = pu0.v;
            pf[qs][1] = pu1.v;
        }

        // ---- O^T += V^T P^T : one V-read feeds both q-subtiles ----
        __builtin_amdgcn_s_setprio(1);
#pragma unroll
        for (int cc = 0; cc < 2; ++cc)
#pragma unroll
            for (int j = 0; j < 8; ++j) {
                int r = 8 * j + (lq >> 1);                  // pair-row
                int slot = (((lq & 1) << 3) | (4 * cc + lh)) ^ (r & 7);
                f16x8 vf = *(const f16x8*)&V[r * 128 + slot * 8];
                Ot[0][j] = __builtin_amdgcn_mfma_f32_16x16x32_f16(vf, pf[0][cc], Ot[0][j], 0, 0, 0);
                Ot[1][j] = __builtin_amdgcn_mfma_f32_16x16x32_f16(vf, pf[1][cc], Ot[1][j], 0, 0, 0);
            }
        __builtin_amdgcn_s_setprio(0);
    }

    // ---- partial store: part[sp][b][q][d] f16, ml[sp][b][q] = {m,l} ----
#pragma unroll
    for (int qs = 0; qs < 2; ++qs) {
        u16* pb = part + (((size_t)sp * B_ + b) * N_ + q0w + 16 * qs + lq) * D_;
#pragma unroll
        for (int j = 0; j < 8; ++j) {
            uint2 pk2;
            pk2.x = pkrtz(Ot[qs][j][0], Ot[qs][j][1]);
            pk2.y = pkrtz(Ot[qs][j][2], Ot[qs][j][3]);
            *(uint2*)(pb + 16 * j + 4 * lh) = pk2;
        }
        if (lh == 0) {
            float* mp = ml + (((size_t)sp * B_ + b) * N_ + q0w + 16 * qs + lq) * 2;
            mp[0] = m_run[qs];
            mp[1] = l_run[qs];
        }
    }
}

// ---------------------------------------------------------------------------
// Fused merge (4 splits) + Wz conv1x1 + BN partial sums.  (r18 version)
// grid (N/64, B), block 512 (8 waves); weights hoisted; 8-replica atomics.
// ---------------------------------------------------------------------------
__global__ __launch_bounds__(512) void wz_kernel(
    const u16* __restrict__ part, const float* __restrict__ ml,
    const float* __restrict__ wz_w, const float* __restrict__ wz_b,
    u16* __restrict__ w_y, float* __restrict__ sums8)
{
    __shared__ u16 ylds[64 * 128];
    const int n0 = blockIdx.x * 64, b = blockIdx.y;
    const int t = threadIdx.x, lane = t & 63, wv = t >> 6;   // wv 0..7
    const int lq = lane & 15, lh = lane >> 4;
    const int rep = blockIdx.x & 7;

    f16x8 wf[4][2];
#pragma unroll
    for (int k = 0; k < 4; ++k)
#pragma unroll
        for (int mm = 0; mm < 2; ++mm) {
            const float* wp = wz_w + (size_t)(16 * (2 * wv + mm) + lq) * CI_ + 32 * k + 8 * lh;
            float4 a = *(const float4*)wp;
            float4 bq = *(const float4*)(wp + 4);
            wf[k][mm][0] = (f16)a.x;  wf[k][mm][1] = (f16)a.y;
            wf[k][mm][2] = (f16)a.z;  wf[k][mm][3] = (f16)a.w;
            wf[k][mm][4] = (f16)bq.x; wf[k][mm][5] = (f16)bq.y;
            wf[k][mm][6] = (f16)bq.z; wf[k][mm][7] = (f16)bq.w;
        }

#pragma unroll
    for (int i = 0; i < 2; ++i) {
        int flat = i * 512 + t;
        int row = flat >> 4, s = flat & 15;
        int q = n0 + row;
        float2 mls[KVSPLIT];
        float m = -INFINITY;
#pragma unroll
        for (int sp = 0; sp < KVSPLIT; ++sp) {
            mls[sp] = *(const float2*)(ml + (((size_t)sp * B_ + b) * N_ + q) * 2);
            m = fmaxf(m, mls[sp].x);
        }
        float wts[KVSPLIT], denom = 0.f;
#pragma unroll
        for (int sp = 0; sp < KVSPLIT; ++sp) {
            wts[sp] = exp2f(mls[sp].x - m);
            denom += wts[sp] * mls[sp].y;
        }
        float inv = 1.f / denom;
        float acc8[8];
#pragma unroll
        for (int e = 0; e < 8; ++e) acc8[e] = 0.f;
#pragma unroll
        for (int sp = 0; sp < KVSPLIT; ++sp) {
            f16x8 o = *(const f16x8*)(part + (((size_t)sp * B_ + b) * N_ + q) * D_ + 8 * s);
#pragma unroll
            for (int e = 0; e < 8; ++e) acc8[e] += wts[sp] * (float)o[e];
        }
        union { f16 h[8]; f16x8 v; } mv;
#pragma unroll
        for (int e = 0; e < 8; ++e) mv.h[e] = (f16)(acc8[e] * inv);
        *(f16x8*)&ylds[row * 128 + 8 * (s ^ (row & 7))] = mv.v;
    }
    __syncthreads();

    f32x4 acc[2][4];
#pragma unroll
    for (int mm = 0; mm < 2; ++mm) {
        float b0 = wz_b[16 * (2 * wv + mm) + 4 * lh + 0];
        float b1 = wz_b[16 * (2 * wv + mm) + 4 * lh + 1];
        float b2 = wz_b[16 * (2 * wv + mm) + 4 * lh + 2];
        float b3 = wz_b[16 * (2 * wv + mm) + 4 * lh + 3];
#pragma unroll
        for (int s = 0; s < 4; ++s) acc[mm][s] = (f32x4){b0, b1, b2, b3};
    }

#pragma unroll
    for (int k = 0; k < 4; ++k)
#pragma unroll
        for (int s = 0; s < 4; ++s) {
            int row = 16 * s + lq;
            f16x8 yf = *(const f16x8*)&ylds[row * 128 + 8 * ((4 * k + lh) ^ (row & 7))];
#pragma unroll
            for (int mm = 0; mm < 2; ++mm)
                acc[mm][s] = __builtin_amdgcn_mfma_f32_16x16x32_f16(wf[k][mm], yf, acc[mm][s], 0, 0, 0);
        }

#pragma unroll
    for (int mm = 0; mm < 2; ++mm) {
        int cb = 16 * (2 * wv + mm) + 4 * lh;
#pragma unroll
        for (int s = 0; s < 4; ++s) {
            int n = n0 + 16 * s + lq;
#pragma unroll
            for (int r = 0; r < 4; ++r)
                w_y[((size_t)b * C_ + cb + r) * N_ + n] = f2h(acc[mm][s][r]);
        }
#pragma unroll
        for (int r = 0; r < 4; ++r) {
            float sv = acc[mm][0][r] + acc[mm][1][r] + acc[mm][2][r] + acc[mm][3][r];
            float qv = acc[mm][0][r] * acc[mm][0][r] + acc[mm][1][r] * acc[mm][1][r]
                     + acc[mm][2][r] * acc[mm][2][r] + acc[mm][3][r] * acc[mm][3][r];
#pragma unroll
            for (int d = 1; d < 16; d <<= 1) {
                sv += __shfl_xor(sv, d);
                qv += __shfl_xor(qv, d);
            }
            if (lq == 0) {
                atomicAdd(&sums8[rep * 512 + cb + r], sv);
                atomicAdd(&sums8[rep * 512 + C_ + cb + r], qv);
            }
        }
    }
}

// ---------------------------------------------------------------------------
// BN finalize + residual (w_y f16; sums in 8 replicas)
// ---------------------------------------------------------------------------
__global__ __launch_bounds__(256) void final_kernel(
    const u16* __restrict__ w_y, const float* __restrict__ src,
    const float* __restrict__ gamma, const float* __restrict__ beta,
    const float* __restrict__ sums8, float* __restrict__ out)
{
    const float invN = 1.0f / (float)(B_ * N_);
    size_t i8 = ((size_t)blockIdx.x * blockDim.x + threadIdx.x) * 8;
    if (i8 >= (size_t)B_ * C_ * N_) return;
    int c = (int)((i8 / N_) % C_);
    float ssum = 0.f, ssq = 0.f;
#pragma unroll
    for (int rp = 0; rp < 8; ++rp) {
        ssum += sums8[rp * 512 + c];
        ssq  += sums8[rp * 512 + C_ + c];
    }
    float mean  = ssum * invN;
    float var   = ssq * invN - mean * mean;
    float scale = rsqrtf(var + 1e-5f) * gamma[c];
    float bb    = beta[c];
    f16x8 w = *(const f16x8*)(w_y + i8);
    float4 s0 = *(const float4*)(src + i8);
    float4 s1 = *(const float4*)(src + i8 + 4);
    float4 o0, o1;
    o0.x = ((float)w[0] - mean) * scale + bb + s0.x;
    o0.y = ((float)w[1] - mean) * scale + bb + s0.y;
    o0.z = ((float)w[2] - mean) * scale + bb + s0.z;
    o0.w = ((float)w[3] - mean) * scale + bb + s0.w;
    o1.x = ((float)w[4] - mean) * scale + bb + s1.x;
    o1.y = ((float)w[5] - mean) * scale + bb + s1.y;
    o1.z = ((float)w[6] - mean) * scale + bb + s1.z;
    o1.w = ((float)w[7] - mean) * scale + bb + s1.w;
    *(float4*)(out + i8)     = o0;
    *(float4*)(out + i8 + 4) = o1;
}

extern "C" void kernel_launch(void* const* d_in, const int* in_sizes, int n_in,
                              void* d_out, int out_size, void* d_ws, size_t ws_size,
                              hipStream_t stream)
{
    const float* x     = (const float*)d_in[0];
    const float* src   = (const float*)d_in[1];
    const float* g_w   = (const float*)d_in[2];
    const float* g_b   = (const float*)d_in[3];
    const float* th_w  = (const float*)d_in[4];
    const float* th_b  = (const float*)d_in[5];
    const float* ph_w  = (const float*)d_in[6];
    const float* ph_b  = (const float*)d_in[7];
    const float* wz_w  = (const float*)d_in[8];
    const float* wz_b  = (const float*)d_in[9];
    const float* gamma = (const float*)d_in[10];
    const float* beta  = (const float*)d_in[11];

    char* ws = (char*)d_ws;
    u16*   th    = (u16*)(ws + (0u  << 20));    //  4 MB (dead after attn)
    u16*   ph    = (u16*)(ws + (4u  << 20));    //  4 MB (dead after attn)
    u16*   gt    = (u16*)(ws + (8u  << 20));    //  4 MB (dead after attn)
    u16*   part  = (u16*)(ws + (12u << 20));    // 16 MB [4][B][N][D] f16
    float* mlbuf = (float*)(ws + (28u << 20));  // 512 KB [4][B][N][2]
    u16*   w_y   = (u16*)(ws + (0u  << 20));    //  8 MB f16, aliases th+ph
    float* sums8 = (float*)(ws + (28u << 20) + (1u << 19)); // 16 KB [8][512]

    hipMemsetAsync(sums8, 0, 8 * 2 * C_ * sizeof(float), stream);

    embed_kernel<<<dim3(64, 4, 3), 256, 0, stream>>>(
        x, src, g_w, g_b, th_w, th_b, ph_w, ph_b, th, ph, gt);
    attn_kernel<<<dim3(N_ / 128, B_, KVSPLIT), 256, 0, stream>>>(
        th, ph, gt, part, mlbuf);
    wz_kernel<<<dim3(N_ / 64, B_), 512, 0, stream>>>(part, mlbuf, wz_w, wz_b, w_y, sums8);
    final_kernel<<<2048, 256, 0, stream>>>(w_y, src, gamma, beta, sums8, (float*)d_out);
}

// Round 22
// 103.857 us; speedup vs baseline: 1.0121x; 1.0121x over previous
//
#include <hip/hip_runtime.h>
#include <math.h>

#define B_  4
#define C_  256
#define CI_ 128
#define N_  4096
#define D_  128
#define KVSPLIT 4
#define KVQ  (N_ / KVSPLIT)
#define KVT  64
#define NT   (KVQ / KVT)
#define LOG2E 1.4426950408889634f

typedef _Float16 f16;
typedef f16 f16x8 __attribute__((ext_vector_type(8)));
typedef __fp16 fp16x2 __attribute__((ext_vector_type(2)));
typedef float f32x4 __attribute__((ext_vector_type(4)));
typedef unsigned short u16;

__device__ __forceinline__ u16 f2h(float x) {
    union { f16 h; u16 u; } v; v.h = (f16)x; return v.u;
}
__device__ __forceinline__ unsigned pkrtz(float a, float b) {
    union { fp16x2 h; unsigned u; } v;
    v.h = __builtin_amdgcn_cvt_pkrtz(a, b);
    return v.u;
}

__device__ __forceinline__ void gll16(const void* g, void* l) {
    __builtin_amdgcn_global_load_lds(
        (const __attribute__((address_space(1))) void*)g,
        (__attribute__((address_space(3))) void*)l, 16, 0, 0);
}

// ---------------------------------------------------------------------------
// Embedding conv1x1, f16 MFMA, double-buffered LDS (1 barrier/chunk),
// balanced: one conv per grid plane.  grid (N/64, B, 3), block 256.
// which 0: theta(x)*LOG2E -> th[n][ci]; 1: phi(src) -> ph[n][ci];
// which 2: g(src) -> gt[ci][n].   (round-21 version, kept)
// ---------------------------------------------------------------------------
__global__ __launch_bounds__(256) void embed_kernel(
    const float* __restrict__ x, const float* __restrict__ src,
    const float* __restrict__ g_w, const float* __restrict__ g_b,
    const float* __restrict__ th_w, const float* __restrict__ th_b,
    const float* __restrict__ ph_w, const float* __restrict__ ph_b,
    u16* __restrict__ th, u16* __restrict__ ph, u16* __restrict__ gt)
{
    __shared__ u16 xh[2][64 * 40];

    const int n0 = blockIdx.x * 64, b = blockIdx.y, which = blockIdx.z;
    const float* in   = which ? src : x;
    const float* wm   = (which == 0) ? th_w : (which == 1 ? ph_w : g_w);
    const float* bias = (which == 0) ? th_b : (which == 1 ? ph_b : g_b);
    const float wscale = (which == 0) ? LOG2E : 1.0f;

    const int t = threadIdx.x, lane = t & 63, wv = t >> 6;
    const int lq = lane & 15, lh = lane >> 4;
    const int mf0 = wv * 2, cq = t >> 6;

    f32x4 acc[2][4];
#pragma unroll
    for (int m = 0; m < 2; ++m) {
        float b0 = bias[16 * (mf0 + m) + 4 * lh + 0] * wscale;
        float b1 = bias[16 * (mf0 + m) + 4 * lh + 1] * wscale;
        float b2 = bias[16 * (mf0 + m) + 4 * lh + 2] * wscale;
        float b3 = bias[16 * (mf0 + m) + 4 * lh + 3] * wscale;
#pragma unroll
        for (int s = 0; s < 4; ++s) acc[m][s] = (f32x4){b0, b1, b2, b3};
    }

    const float* colbase = in + (size_t)b * C_ * N_ + n0;

    float iv[2][8];
    f16x8 wf_[2][2];

    auto load_inputs = [&](int slot, int k) {
        const int c0 = k * 32;
#pragma unroll
        for (int p = 0; p < 2; ++p) {
            int cl = 16 * p + 4 * cq;
#pragma unroll
            for (int e = 0; e < 4; ++e)
                iv[slot][4 * p + e] = colbase[(size_t)(c0 + cl + e) * N_ + lane];
        }
    };
    auto load_weights = [&](int slot, int k) {
        const int c0 = k * 32;
#pragma unroll
        for (int m = 0; m < 2; ++m) {
            const float* wp = wm + (size_t)(16 * (mf0 + m) + lq) * C_ + c0 + 8 * lh;
            float4 a = *(const float4*)wp;
            float4 bq = *(const float4*)(wp + 4);
            wf_[slot][m][0] = (f16)(a.x * wscale);  wf_[slot][m][1] = (f16)(a.y * wscale);
            wf_[slot][m][2] = (f16)(a.z * wscale);  wf_[slot][m][3] = (f16)(a.w * wscale);
            wf_[slot][m][4] = (f16)(bq.x * wscale); wf_[slot][m][5] = (f16)(bq.y * wscale);
            wf_[slot][m][6] = (f16)(bq.z * wscale); wf_[slot][m][7] = (f16)(bq.w * wscale);
        }
    };
    auto write_lds = [&](int slot) {
#pragma unroll
        for (int p = 0; p < 2; ++p) {
            int cl = 16 * p + 4 * cq;
            union { f16 h[4]; ushort4 u; } cv;
            cv.h[0] = (f16)iv[slot][4 * p + 0];
            cv.h[1] = (f16)iv[slot][4 * p + 1];
            cv.h[2] = (f16)iv[slot][4 * p + 2];
            cv.h[3] = (f16)iv[slot][4 * p + 3];
            *(ushort4*)&xh[slot][lane * 40 + cl] = cv.u;
        }
    };

    // prologue: chunk 0 -> slot 0 (regs + LDS), chunk 1 -> slot 1 (regs)
    load_inputs(0, 0);
    load_weights(0, 0);
    write_lds(0);
    load_inputs(1, 1);
    load_weights(1, 1);

#pragma unroll
    for (int k = 0; k < 8; ++k) {
        const int cur = k & 1, nxt = cur ^ 1;
        __syncthreads();                 // xh[cur] writes visible; xh[nxt] free
        if (k < 7) write_lds(nxt);       // chunk k+1 regs -> LDS
        if (k < 6) load_inputs(cur, k + 2);   // iv[cur] dead -> prefetch k+2

#pragma unroll
        for (int s = 0; s < 4; ++s) {
            f16x8 xf = *(const f16x8*)&xh[cur][(16 * s + lq) * 40 + 8 * lh];
#pragma unroll
            for (int m = 0; m < 2; ++m)
                acc[m][s] = __builtin_amdgcn_mfma_f32_16x16x32_f16(wf_[cur][m], xf, acc[m][s], 0, 0, 0);
        }
        if (k < 6) load_weights(cur, k + 2);  // wf_[cur] consumed by MFMA above
    }

    // epilogue. D-layout: col(n)=lq, row(ci)=16*mf+4*lh+reg
    if (which < 2) {
        u16* op = (which == 0 ? th : ph) + (size_t)b * N_ * CI_;
#pragma unroll
        for (int m = 0; m < 2; ++m)
#pragma unroll
            for (int s = 0; s < 4; ++s) {
                ushort4 pk = {f2h(acc[m][s][0]), f2h(acc[m][s][1]),
                              f2h(acc[m][s][2]), f2h(acc[m][s][3])};
                *(ushort4*)(op + (size_t)(n0 + 16 * s + lq) * CI_ + 16 * (mf0 + m) + 4 * lh) = pk;
            }
    } else {
        u16* gb2 = gt + (size_t)b * CI_ * N_;
#pragma unroll
        for (int m = 0; m < 2; ++m)
#pragma unroll
            for (int s = 0; s < 4; ++s)
#pragma unroll
                for (int r = 0; r < 4; ++r)
                    gb2[(size_t)(16 * (mf0 + m) + 4 * lh + r) * N_ + n0 + 16 * s + lq] =
                        f2h(acc[m][s][r]);
    }
}

// ---------------------------------------------------------------------------
// Flash attention, f16 MFMA, single-barrier double-buffered, KVT=64.
// grid (N/128, B, 4), block 256 (4 waves x 32 q).  EXACT round-19 kernel
// (proven 63.5 us; setprio reverted -- m190 lockstep regime, it hurt).
// ---------------------------------------------------------------------------
__global__ __launch_bounds__(256, 2) void attn_kernel(
    const u16* __restrict__ th, const u16* __restrict__ ph,
    const u16* __restrict__ gt, u16* __restrict__ part, float* __restrict__ ml)
{
    __shared__ u16 Ks[2][KVT * 128];     // 2 x 16KB, row rr: 128 u16
    __shared__ u16 Vt[2][64 * 128];      // 2 x 16KB, pair-row: 2d x 64kv
    __shared__ unsigned Pl[4][16 * 36];  // 9KB, per-wave P exchange

    const int n0 = blockIdx.x * 128, b = blockIdx.y, sp = blockIdx.z;
    const int t = threadIdx.x, wv = t >> 6, lane = t & 63;
    const int lq = lane & 15, lh = lane >> 4;
    const int q0w = n0 + wv * 32;

    const u16* kb = ph + ((size_t)b * N_ + (size_t)sp * KVQ) * D_;
    const u16* vb = gt + (size_t)b * D_ * N_ + sp * KVQ;

    f16x8 qf[2][4];
#pragma unroll
    for (int qs = 0; qs < 2; ++qs) {
        const u16* qp = th + ((size_t)b * N_ + q0w + 16 * qs + lq) * D_ + 8 * lh;
#pragma unroll
        for (int c = 0; c < 4; ++c) qf[qs][c] = *(const f16x8*)(qp + 32 * c);
    }

    f32x4 Ot[2][8];
#pragma unroll
    for (int qs = 0; qs < 2; ++qs)
#pragma unroll
        for (int j = 0; j < 8; ++j) Ot[qs][j] = (f32x4){0.f, 0.f, 0.f, 0.f};
    float m_run[2] = {-INFINITY, -INFINITY};
    float l_run[2] = {0.f, 0.f};

    auto stage = [&](int buf, int it) {
        const int kv0 = it * KVT;
#pragma unroll
        for (int ii = 0; ii < 4; ++ii) {
            int i = 4 * wv + ii;                    // 0..15
            int rr = 4 * i + (lane >> 4);           // kv row 0..63
            const u16* g = kb + (size_t)(kv0 + rr) * D_ + (((lane & 15) ^ (rr & 7)) * 8);
            gll16(g, &Ks[buf][i * 512]);
        }
#pragma unroll
        for (int jj = 0; jj < 4; ++jj) {
            int j = 4 * wv + jj;                    // 0..15, 4 pair-rows each
            int r = 4 * j + (lane >> 4);            // pair-row 0..63 (256B rows)
            int s = lane & 15;                      // linear slot (16B)
            int c6 = s ^ (r & 7);                   // swizzled logical slot
            int dd = 2 * r + (c6 >> 3);             // d row 0..127
            const u16* g = vb + (size_t)dd * N_ + kv0 + (c6 & 7) * 8;
            gll16(g, &Vt[buf][j * 512]);
        }
    };

    stage(0, 0);
    for (int it = 0; it < NT; ++it) {
        __syncthreads();                       // drains vmcnt -> buf[it&1] ready
        if (it + 1 < NT) stage((it + 1) & 1, it + 1);   // flies under compute
        const u16* K = Ks[it & 1];
        const u16* V = Vt[it & 1];

        // ---- S^T = K Q^T : lane holds S(q=lq, kv=16tt+4lh+r), tt 0..3 ----
        f32x4 S[2][4];
#pragma unroll
        for (int qs = 0; qs < 2; ++qs)
#pragma unroll
            for (int tt = 0; tt < 4; ++tt) S[qs][tt] = (f32x4){0.f, 0.f, 0.f, 0.f};
#pragma unroll
        for (int c = 0; c < 4; ++c)
#pragma unroll
            for (int tt = 0; tt < 4; ++tt) {
                int row = 16 * tt + lq;
                f16x8 kf = *(const f16x8*)&K[row * 128 + ((32 * c + 8 * lh) ^ ((row & 7) << 3))];
                S[0][tt] = __builtin_amdgcn_mfma_f32_16x16x32_f16(kf, qf[0][c], S[0][tt], 0, 0, 0);
                S[1][tt] = __builtin_amdgcn_mfma_f32_16x16x32_f16(kf, qf[1][c], S[1][tt], 0, 0, 0);
            }

        // ---- per-lane online softmax (base-2) + P exchange via wave-LDS ----
        f16x8 pf[2][2];
#pragma unroll
        for (int qs = 0; qs < 2; ++qs) {
            float mx = -INFINITY;
#pragma unroll
            for (int tt = 0; tt < 4; ++tt)
#pragma unroll
                for (int r = 0; r < 4; ++r) mx = fmaxf(mx, S[qs][tt][r]);
            mx = fmaxf(mx, __shfl_xor(mx, 16));
            mx = fmaxf(mx, __shfl_xor(mx, 32));
            if (!__all(mx <= m_run[qs])) {       // exact skip: al==1 otherwise
                float mn = fmaxf(m_run[qs], mx);
                float al = exp2f(m_run[qs] - mn);
                m_run[qs] = mn;
                l_run[qs] *= al;
#pragma unroll
                for (int j = 0; j < 8; ++j) Ot[qs][j] *= al;
            }
            float p[4][4];
            float ls = 0.f;
#pragma unroll
            for (int tt = 0; tt < 4; ++tt)
#pragma unroll
                for (int r = 0; r < 4; ++r) {
                    p[tt][r] = exp2f(S[qs][tt][r] - m_run[qs]);
                    ls += p[tt][r];
                }
            ls += __shfl_xor(ls, 16);
            ls += __shfl_xor(ls, 32);
            l_run[qs] += ls;

            // write P pairs: row q=lq (stride 36 u32), u32 idx 8tt+2lh+{0,1}
            unsigned* pw = &Pl[wv][lq * 36];
#pragma unroll
            for (int tt = 0; tt < 4; ++tt) {
                uint2 wpair;
                wpair.x = pkrtz(p[tt][0], p[tt][1]);
                wpair.y = pkrtz(p[tt][2], p[tt][3]);
                *(uint2*)(pw + 8 * tt + 2 * lh) = wpair;     // ds_write_b64
            }
            // read B-frags: kv = 32cc + 8lh..+7 -> u32 16cc + 4lh..+3
            union { uint4 u; f16x8 v; } pu0, pu1;
            pu0.u = *(const uint4*)(pw + 4 * lh);            // ds_read_b128
            pu1.u = *(const uint4*)(pw + 16 + 4 * lh);
            pf[qs][0] = pu0.v;
            pf[qs][1] = pu1.v;
        }

        // ---- O^T += V^T P^T : one V-read feeds both q-subtiles ----
#pragma unroll
        for (int cc = 0; cc < 2; ++cc)
#pragma unroll
            for (int j = 0; j < 8; ++j) {
                int r = 8 * j + (lq >> 1);                  // pair-row
                int slot = (((lq & 1) << 3) | (4 * cc + lh)) ^ (r & 7);
                f16x8 vf = *(const f16x8*)&V[r * 128 + slot * 8];
                Ot[0][j] = __builtin_amdgcn_mfma_f32_16x16x32_f16(vf, pf[0][cc], Ot[0][j], 0, 0, 0);
                Ot[1][j] = __builtin_amdgcn_mfma_f32_16x16x32_f16(vf, pf[1][cc], Ot[1][j], 0, 0, 0);
            }
    }

    // ---- partial store: part[sp][b][q][d] f16, ml[sp][b][q] = {m,l} ----
#pragma unroll
    for (int qs = 0; qs < 2; ++qs) {
        u16* pb = part + (((size_t)sp * B_ + b) * N_ + q0w + 16 * qs + lq) * D_;
#pragma unroll
        for (int j = 0; j < 8; ++j) {
            uint2 pk2;
            pk2.x = pkrtz(Ot[qs][j][0], Ot[qs][j][1]);
            pk2.y = pkrtz(Ot[qs][j][2], Ot[qs][j][3]);
            *(uint2*)(pb + 16 * j + 4 * lh) = pk2;
        }
        if (lh == 0) {
            float* mp = ml + (((size_t)sp * B_ + b) * N_ + q0w + 16 * qs + lq) * 2;
            mp[0] = m_run[qs];
            mp[1] = l_run[qs];
        }
    }
}

// ---------------------------------------------------------------------------
// Fused merge (4 splits) + Wz conv1x1 + BN partial sums.  (r18 version)
// grid (N/64, B), block 512 (8 waves); weights hoisted; 8-replica atomics.
// ---------------------------------------------------------------------------
__global__ __launch_bounds__(512) void wz_kernel(
    const u16* __restrict__ part, const float* __restrict__ ml,
    const float* __restrict__ wz_w, const float* __restrict__ wz_b,
    u16* __restrict__ w_y, float* __restrict__ sums8)
{
    __shared__ u16 ylds[64 * 128];
    const int n0 = blockIdx.x * 64, b = blockIdx.y;
    const int t = threadIdx.x, lane = t & 63, wv = t >> 6;   // wv 0..7
    const int lq = lane & 15, lh = lane >> 4;
    const int rep = blockIdx.x & 7;

    f16x8 wf[4][2];
#pragma unroll
    for (int k = 0; k < 4; ++k)
#pragma unroll
        for (int mm = 0; mm < 2; ++mm) {
            const float* wp = wz_w + (size_t)(16 * (2 * wv + mm) + lq) * CI_ + 32 * k + 8 * lh;
            float4 a = *(const float4*)wp;
            float4 bq = *(const float4*)(wp + 4);
            wf[k][mm][0] = (f16)a.x;  wf[k][mm][1] = (f16)a.y;
            wf[k][mm][2] = (f16)a.z;  wf[k][mm][3] = (f16)a.w;
            wf[k][mm][4] = (f16)bq.x; wf[k][mm][5] = (f16)bq.y;
            wf[k][mm][6] = (f16)bq.z; wf[k][mm][7] = (f16)bq.w;
        }

#pragma unroll
    for (int i = 0; i < 2; ++i) {
        int flat = i * 512 + t;
        int row = flat >> 4, s = flat & 15;
        int q = n0 + row;
        float2 mls[KVSPLIT];
        float m = -INFINITY;
#pragma unroll
        for (int sp = 0; sp < KVSPLIT; ++sp) {
            mls[sp] = *(const float2*)(ml + (((size_t)sp * B_ + b) * N_ + q) * 2);
            m = fmaxf(m, mls[sp].x);
        }
        float wts[KVSPLIT], denom = 0.f;
#pragma unroll
        for (int sp = 0; sp < KVSPLIT; ++sp) {
            wts[sp] = exp2f(mls[sp].x - m);
            denom += wts[sp] * mls[sp].y;
        }
        float inv = 1.f / denom;
        float acc8[8];
#pragma unroll
        for (int e = 0; e < 8; ++e) acc8[e] = 0.f;
#pragma unroll
        for (int sp = 0; sp < KVSPLIT; ++sp) {
            f16x8 o = *(const f16x8*)(part + (((size_t)sp * B_ + b) * N_ + q) * D_ + 8 * s);
#pragma unroll
            for (int e = 0; e < 8; ++e) acc8[e] += wts[sp] * (float)o[e];
        }
        union { f16 h[8]; f16x8 v; } mv;
#pragma unroll
        for (int e = 0; e < 8; ++e) mv.h[e] = (f16)(acc8[e] * inv);
        *(f16x8*)&ylds[row * 128 + 8 * (s ^ (row & 7))] = mv.v;
    }
    __syncthreads();

    f32x4 acc[2][4];
#pragma unroll
    for (int mm = 0; mm < 2; ++mm) {
        float b0 = wz_b[16 * (2 * wv + mm) + 4 * lh + 0];
        float b1 = wz_b[16 * (2 * wv + mm) + 4 * lh + 1];
        float b2 = wz_b[16 * (2 * wv + mm) + 4 * lh + 2];
        float b3 = wz_b[16 * (2 * wv + mm) + 4 * lh + 3];
#pragma unroll
        for (int s = 0; s < 4; ++s) acc[mm][s] = (f32x4){b0, b1, b2, b3};
    }

#pragma unroll
    for (int k = 0; k < 4; ++k)
#pragma unroll
        for (int s = 0; s < 4; ++s) {
            int row = 16 * s + lq;
            f16x8 yf = *(const f16x8*)&ylds[row * 128 + 8 * ((4 * k + lh) ^ (row & 7))];
#pragma unroll
            for (int mm = 0; mm < 2; ++mm)
                acc[mm][s] = __builtin_amdgcn_mfma_f32_16x16x32_f16(wf[k][mm], yf, acc[mm][s], 0, 0, 0);
        }

#pragma unroll
    for (int mm = 0; mm < 2; ++mm) {
        int cb = 16 * (2 * wv + mm) + 4 * lh;
#pragma unroll
        for (int s = 0; s < 4; ++s) {
            int n = n0 + 16 * s + lq;
#pragma unroll
            for (int r = 0; r < 4; ++r)
                w_y[((size_t)b * C_ + cb + r) * N_ + n] = f2h(acc[mm][s][r]);
        }
#pragma unroll
        for (int r = 0; r < 4; ++r) {
            float sv = acc[mm][0][r] + acc[mm][1][r] + acc[mm][2][r] + acc[mm][3][r];
            float qv = acc[mm][0][r] * acc[mm][0][r] + acc[mm][1][r] * acc[mm][1][r]
                     + acc[mm][2][r] * acc[mm][2][r] + acc[mm][3][r] * acc[mm][3][r];
#pragma unroll
            for (int d = 1; d < 16; d <<= 1) {
                sv += __shfl_xor(sv, d);
                qv += __shfl_xor(qv, d);
            }
            if (lq == 0) {
                atomicAdd(&sums8[rep * 512 + cb + r], sv);
                atomicAdd(&sums8[rep * 512 + C_ + cb + r], qv);
            }
        }
    }
}

// ---------------------------------------------------------------------------
// BN finalize + residual (w_y f16; sums in 8 replicas)
// ---------------------------------------------------------------------------
__global__ __launch_bounds__(256) void final_kernel(
    const u16* __restrict__ w_y, const float* __restrict__ src,
    const float* __restrict__ gamma, const float* __restrict__ beta,
    const float* __restrict__ sums8, float* __restrict__ out)
{
    const float invN = 1.0f / (float)(B_ * N_);
    size_t i8 = ((size_t)blockIdx.x * blockDim.x + threadIdx.x) * 8;
    if (i8 >= (size_t)B_ * C_ * N_) return;
    int c = (int)((i8 / N_) % C_);
    float ssum = 0.f, ssq = 0.f;
#pragma unroll
    for (int rp = 0; rp < 8; ++rp) {
        ssum += sums8[rp * 512 + c];
        ssq  += sums8[rp * 512 + C_ + c];
    }
    float mean  = ssum * invN;
    float var   = ssq * invN - mean * mean;
    float scale = rsqrtf(var + 1e-5f) * gamma[c];
    float bb    = beta[c];
    f16x8 w = *(const f16x8*)(w_y + i8);
    float4 s0 = *(const float4*)(src + i8);
    float4 s1 = *(const float4*)(src + i8 + 4);
    float4 o0, o1;
    o0.x = ((float)w[0] - mean) * scale + bb + s0.x;
    o0.y = ((float)w[1] - mean) * scale + bb + s0.y;
    o0.z = ((float)w[2] - mean) * scale + bb + s0.z;
    o0.w = ((float)w[3] - mean) * scale + bb + s0.w;
    o1.x = ((float)w[4] - mean) * scale + bb + s1.x;
    o1.y = ((float)w[5] - mean) * scale + bb + s1.y;
    o1.z = ((float)w[6] - mean) * scale + bb + s1.z;
    o1.w = ((float)w[7] - mean) * scale + bb + s1.w;
    *(float4*)(out + i8)     = o0;
    *(float4*)(out + i8 + 4) = o1;
}

extern "C" void kernel_launch(void* const* d_in, const int* in_sizes, int n_in,
                              void* d_out, int out_size, void* d_ws, size_t ws_size,
                              hipStream_t stream)
{
    const float* x     = (const float*)d_in[0];
    const float* src   = (const float*)d_in[1];
    const float* g_w   = (const float*)d_in[2];
    const float* g_b   = (const float*)d_in[3];
    const float* th_w  = (const float*)d_in[4];
    const float* th_b  = (const float*)d_in[5];
    const float* ph_w  = (const float*)d_in[6];
    const float* ph_b  = (const float*)d_in[7];
    const float* wz_w  = (const float*)d_in[8];
    const float* wz_b  = (const float*)d_in[9];
    const float* gamma = (const float*)d_in[10];
    const float* beta  = (const float*)d_in[11];

    char* ws = (char*)d_ws;
    u16*   th    = (u16*)(ws + (0u  << 20));    //  4 MB (dead after attn)
    u16*   ph    = (u16*)(ws + (4u  << 20));    //  4 MB (dead after attn)
    u16*   gt    = (u16*)(ws + (8u  << 20));    //  4 MB (dead after attn)
    u16*   part  = (u16*)(ws + (12u << 20));    // 16 MB [4][B][N][D] f16
    float* mlbuf = (float*)(ws + (28u << 20));  // 512 KB [4][B][N][2]
    u16*   w_y   = (u16*)(ws + (0u  << 20));    //  8 MB f16, aliases th+ph
    float* sums8 = (float*)(ws + (28u << 20) + (1u << 19)); // 16 KB [8][512]

    hipMemsetAsync(sums8, 0, 8 * 2 * C_ * sizeof(float), stream);

    embed_kernel<<<dim3(64, 4, 3), 256, 0, stream>>>(
        x, src, g_w, g_b, th_w, th_b, ph_w, ph_b, th, ph, gt);
    attn_kernel<<<dim3(N_ / 128, B_, KVSPLIT), 256, 0, stream>>>(
        th, ph, gt, part, mlbuf);
    wz_kernel<<<dim3(N_ / 64, B_), 512, 0, stream>>>(part, mlbuf, wz_w, wz_b, w_y, sums8);
    final_kernel<<<2048, 256, 0, stream>>>(w_y, src, gamma, beta, sums8, (float*)d_out);
}